// Round 4
// baseline (131.466 us; speedup 1.0000x reference)
//
#include <hip/hip_runtime.h>

#define T_N     1048576
#define BLK     256
#define S_OUT   8
#define R_BLOCK (BLK * S_OUT)        // 2048 rows per block
#define NB      (T_N / R_BLOCK)      // 512 blocks
#define NTH     (T_N / S_OUT)        // 131072 threads
#define WARM    64                   // 0.71^64 ~ 5e-10 carry-error decay (scan-1 contractive)
#define HALO    (WARM + 4)           // 68 = warm-up + max shift
#define NROWS   (R_BLOCK + HALO)     // 2116 rows staged per block
#define NV      (NROWS * 9 / 4)      // 4761 float4 per block (exactly divisible)
#define LPAD    2384                 // padded column length: 2115 + (2115>>3) = 2379 < 2384
#define NCOL    6                    // cols 0,2,3,4,6,7 -> slots 0..5
#define CID_PREC 4                   // col 6 (prec)
#define CID_TP   5                   // col 7 (total_prec)
// col -> slot nibble LUT: c0->0 c1->F c2->1 c3->2 c4->3 c5->F c6->4 c7->5 c8->F
#define COL_LUT 0xF54F321F0ull
// padded LDS address: lane-stride 8 rows -> effective stride 9, gcd(9,32)=1 -> conflict-free
#define PA(lr)  ((lr) + ((lr) >> 3))

__device__ __forceinline__ float pp_step(float c, float p, float mr, float miss,
                                         float omev, float evc) {
    float last = (c > mr) ? fmaf(c - mr, miss, mr) : c;
    return fmaf(last + p, omev, -evc);
}

__global__ __launch_bounds__(BLK) void k_main(
    const float* __restrict__ x,
    const float* __restrict__ f0p, const float* __restrict__ fcp,
    const float* __restrict__ kp,  const float* __restrict__ nnp,
    const float* __restrict__ dpp, const float* __restrict__ evp,
    const float* __restrict__ evcp,const float* __restrict__ mrp,
    const float* __restrict__ missp,
    const float* __restrict__ wr1p,const float* __restrict__ wr2p,
    const float* __restrict__ wz1p,const float* __restrict__ wz2p,
    const int*   __restrict__ epp,
    float* __restrict__ out, float* __restrict__ Bthr, float* __restrict__ Bblk)
{
    __shared__ float s_x[NCOL * LPAD];   // 57.2 KiB -> 2 blocks/CU (= full residency at NB=512)
    __shared__ float s_B[BLK];

    const int b = blockIdx.x, t = threadIdx.x;
    const int row0 = b * R_BLOCK;

    const float f0 = *f0p, fc = *fcp, kk = *kp, nn = *nnp;
    const float dp = *dpp, ev = *evp, evc = *evcp, mr = *mrp, miss = *missp;
    const float wr1 = *wr1p, wr2 = *wr2p, wz1 = *wz1p, wz2 = *wz2p;
    const int ep = *epp;
    const float omev = 1.0f - ev;
    const float cimp = 1.49f / nn;
    const float f0mfc = f0 - fc;

    const float rid = rintf(x[8]);                    // jnp.round == rint
    const int shift = (rid == 3723.0f || rid == 870.0f) ? 1 : 4;
    const float pp0 = x[7] - x[6];                    // total_prec[0] - prec[0]

    // ---- coalesced raw staging: float4 global loads, transpose into column LDS ----
    // startf = (row0-HALO)*9 is a multiple of 4 (2048*9*b - 612), so float4 loads align.
    const int startf = (row0 - HALO) * 9;
    for (int v = t; v < NV; v += BLK) {
        int g = startf + 4 * v;
        if (g >= 0) {                                 // g<0 slots (block 0 head) never read
            const float4 val = *reinterpret_cast<const float4*>(x + g);
            unsigned ug = (unsigned)g;
            int r   = (int)(ug / 9u);                 // magic-mul div
            int col = (int)(ug - 9u * (unsigned)r);
            int lr  = r - row0 + HALO;
            float fv[4] = {val.x, val.y, val.z, val.w};
            #pragma unroll
            for (int k = 0; k < 4; ++k) {
                int cid = (int)((COL_LUT >> (4 * col)) & 0xFull);
                if (cid < NCOL) s_x[cid * LPAD + PA(lr)] = fv[k];
                col++;
                if (col == 9) { col = 0; lr++; }      // -> cndmask, no branch
            }
        }
    }
    __syncthreads();

    // ---- scan-1: per-thread warm-up (contractive, slope <= 1-ev = 0.71/step) ----
    const int i0 = row0 + t * S_OUT;
    const int rb = i0 - shift;
    int rr = rb - WARM; if (rr < 0) rr = 0;
    float c = (rr == 0) ? pp0 : 0.0f;
    for (; rr < rb; ++rr) {                           // rb<0 -> loop skipped, c stays pp0
        int lr = rr - row0 + HALO;
        c = pp_step(c, s_x[CID_PREC * LPAD + PA(lr)], mr, miss, omev, evc);
    }

    // ---- q (coefs computed from raw columns) + local scan-2; outputs in registers ----
    float outl[S_OUT];
    float h = 0.0f;
    #pragma unroll
    for (int j = 0; j < S_OUT; ++j) {
        const int r = i0 + j - shift;
        float qs = 0.0f;
        if (r >= 0) {
            int a = PA(r - row0 + HALO);              // conflict-free: stride 9 across lanes
            float gl = s_x[0 * LPAD + a];
            float im = s_x[1 * LPAD + a];
            float ar = s_x[2 * LPAD + a];
            float sl = s_x[3 * LPAD + a];
            float pr = s_x[CID_PREC * LPAD + a];
            float tp = s_x[CID_TP   * LPAD + a];
            float pre = fmaxf(c, 0.0f);               // relu'd prec_pre; carry stays raw
            float ft = fmaf(f0mfc, __expf(-kk * tp), fc);
            float cg = gl * ar * (1.0f - ft) * 0.001f;
            float ca = sqrtf(im * ar) * cimp * sqrtf(sl);
            float qg = fmaxf(pre * cg, 0.0f);
            float di = fmaxf(fmaf(pre, 0.001f, -dp), 0.0f);
            float qi = fmaxf(ca * __powf(di, 5.0f / 3.0f), 0.0f);
            qs = qg + qi;
            c = pp_step(c, pr, mr, miss, omev, evc);
        }
        h = fmaf(wr1, h, wr2 * qs);     // q_shift[0]=0 keeps h=0 through i=0 (matches ref)
        outl[j] = (ep > 10) ? fmaf(wz1, h, wz2 * qs) : qs;
    }

    // coalesced store: 2 x float4 per thread, 32B-aligned
    float4* op = reinterpret_cast<float4*>(out + i0);
    op[0] = make_float4(outl[0], outl[1], outl[2], outl[3]);
    op[1] = make_float4(outl[4], outl[5], outl[6], outl[7]);

    // thread aggregate (zero when epoch<=10 so fix-up kernel becomes a pure no-op)
    float Bv = (ep > 10) ? h : 0.0f;
    s_B[t] = Bv;
    Bthr[b * BLK + t] = Bv;
    __syncthreads();
    if (t == 0) {
        const float at = powf(wr1, (float)S_OUT);
        float acc = 0.0f;
        for (int u = 0; u < BLK; ++u) acc = fmaf(at, acc, s_B[u]);
        Bblk[b] = acc;
    }
}

// Cross-block carry propagation + correction: out[i0+j] += wz1 * wr1^(j+1) * h_in.
// Barrier-separated second launch; carries computed thread-parallel (no polling).
__global__ __launch_bounds__(BLK) void k_fix(
    float* __restrict__ out,
    const float* __restrict__ Bthr, const float* __restrict__ Bblk,
    const float* __restrict__ wr1p, const float* __restrict__ wz1p)
{
    __shared__ float sBb[NB];
    __shared__ float sB[BLK];
    __shared__ float carr[BLK];
    __shared__ float sred[BLK];
    const int b = blockIdx.x, t = threadIdx.x;
    const float wr1 = *wr1p, wz1 = *wz1p;
    for (int u = t; u < NB; u += BLK) sBb[u] = Bblk[u];
    sB[t] = Bthr[b * BLK + t];
    __syncthreads();

    // carry into block b = sum_{u<b} agg_u * ab^(b-1-u) — thread-parallel + tree reduce
    const float ab = powf(wr1, (float)R_BLOCK);     // wr1=1 -> exactly 1
    const float at = powf(wr1, (float)S_OUT);
    float partial = 0.0f;
    for (int u = t; u < b; u += BLK)
        partial = fmaf(sBb[u], powf(ab, (float)(b - 1 - u)), partial);
    sred[t] = partial;
    __syncthreads();
    for (int off = BLK / 2; off > 0; off >>= 1) {
        if (t < off) sred[t] += sred[t + off];
        __syncthreads();
    }
    // per-thread carry: serial 256-fma prefix on t0 (~0.4 us, blocks run in parallel)
    if (t == 0) {
        float cth = sred[0];
        for (int u = 0; u < BLK; ++u) { carr[u] = cth; cth = fmaf(at, cth, sB[u]); }
    }
    __syncthreads();

    float hin = carr[t];
    if (hin != 0.0f) {                  // epoch<=10 or true-zero carry: exact no-op
        float4* op = reinterpret_cast<float4*>(out + b * R_BLOCK + t * S_OUT);
        float4 v0 = op[0], v1 = op[1];
        float p = hin * wz1;
        p *= wr1; v0.x += p; p *= wr1; v0.y += p; p *= wr1; v0.z += p; p *= wr1; v0.w += p;
        p *= wr1; v1.x += p; p *= wr1; v1.y += p; p *= wr1; v1.z += p; p *= wr1; v1.w += p;
        op[0] = v0;
        op[1] = v1;
    }
}

extern "C" void kernel_launch(void* const* d_in, const int* in_sizes, int n_in,
                              void* d_out, int out_size, void* d_ws, size_t ws_size,
                              hipStream_t stream) {
    const float* x = (const float*)d_in[0];
    float* out  = (float*)d_out;
    float* Bthr = (float*)d_ws;            // NTH floats (512 KB)
    float* Bblk = Bthr + NTH;              // NB floats

    k_main<<<NB, BLK, 0, stream>>>(x,
        (const float*)d_in[1],  (const float*)d_in[2],  (const float*)d_in[3],
        (const float*)d_in[4],  (const float*)d_in[5],  (const float*)d_in[6],
        (const float*)d_in[7],  (const float*)d_in[8],  (const float*)d_in[9],
        (const float*)d_in[10], (const float*)d_in[11], (const float*)d_in[12],
        (const float*)d_in[13], (const int*)d_in[14],
        out, Bthr, Bblk);

    k_fix<<<NB, BLK, 0, stream>>>(out, Bthr, Bblk,
        (const float*)d_in[10], (const float*)d_in[12]);
}

// Round 5
// 126.699 us; speedup vs baseline: 1.0376x; 1.0376x over previous
//
#include <hip/hip_runtime.h>

#define T_N     1048576
#define BLK     256
#define S_OUT   8
#define R_BLOCK (BLK * S_OUT)        // 2048 rows per block
#define NB      (T_N / R_BLOCK)      // 512 blocks
#define NTH     (T_N / S_OUT)        // 131072 threads
#define WARM    64                   // 0.71^64 ~ 5e-10 carry-error decay (scan-1 contractive)
#define HALO    (WARM + 4)           // warm-up + max shift
#define SW(u)   ((u) + ((u) >> 3))   // LDS swizzle: stride 8 -> 9, gcd(9,32)=1, conflict-free

// R5 = exact R3 kernel (measured best: 123.1 us end-to-end; k_main below top-5 cutoff).
// R4's coalesced-transpose staging regressed (+8 us): both variants run inside the
// poison-fill L3->HBM writeback shadow, so only VALU/scatter overhead past the drain
// matters — R3's precomputed-coefficient staging has the least.

__device__ __forceinline__ float pp_step(float c, float p, float mr, float miss,
                                         float omev, float evc) {
    float last = (c > mr) ? fmaf(c - mr, miss, mr) : c;
    return fmaf(last + p, omev, -evc);
}

__global__ __launch_bounds__(BLK) void k_main(
    const float* __restrict__ x,
    const float* __restrict__ f0p, const float* __restrict__ fcp,
    const float* __restrict__ kp,  const float* __restrict__ nnp,
    const float* __restrict__ dpp, const float* __restrict__ evp,
    const float* __restrict__ evcp,const float* __restrict__ mrp,
    const float* __restrict__ missp,
    const float* __restrict__ wr1p,const float* __restrict__ wr2p,
    const float* __restrict__ wz1p,const float* __restrict__ wz2p,
    const int*   __restrict__ epp,
    float* __restrict__ out, float* __restrict__ Bthr, float* __restrict__ Bblk)
{
    __shared__ float s_prec[SW(R_BLOCK + HALO - 1) + 1];
    __shared__ float s_cG[SW(R_BLOCK + 3) + 1];
    __shared__ float s_cA[SW(R_BLOCK + 3) + 1];
    __shared__ float s_B[BLK];

    const int b = blockIdx.x, t = threadIdx.x;
    const int row0 = b * R_BLOCK;

    const float f0 = *f0p, fc = *fcp, kk = *kp, nn = *nnp;
    const float dp = *dpp, ev = *evp, evc = *evcp, mr = *mrp, miss = *missp;
    const float wr1 = *wr1p, wr2 = *wr2p, wz1 = *wz1p, wz2 = *wz2p;
    const int ep = *epp;
    const float omev = 1.0f - ev;
    const float cimp = 1.49f / nn;
    const float f0mfc = f0 - fc;

    const float rid = rintf(x[8]);                    // jnp.round == rint (half-even)
    const int shift = (rid == 3723.0f || rid == 870.0f) ? 1 : 4;
    const float pp0 = x[7] - x[6];                    // total_prec[0] - prec[0]

    // Stage prec column (scan-1 input) with warm-up halo.
    for (int u = t; u < R_BLOCK + HALO; u += BLK) {
        int r = row0 - HALO + u;
        s_prec[SW(u)] = (r >= 0) ? x[r * 9 + 6] : 0.0f;
    }
    // Stage per-row q coefficients for rows [row0-4, row0+R_BLOCK).
    for (int u = t; u < R_BLOCK + 4; u += BLK) {
        int r = row0 - 4 + u;
        float cg = 0.0f, ca = 0.0f;
        if (r >= 0) {
            const float* row = x + r * 9;
            float gl = row[0], imp = row[2], ar = row[3], sl = row[4], tp = row[7];
            float ft = fmaf(f0mfc, __expf(-kk * tp), fc);
            cg = gl * ar * (1.0f - ft) * 0.001f;
            ca = sqrtf(imp * ar) * cimp * sqrtf(sl);
        }
        s_cG[SW(u)] = cg;
        s_cA[SW(u)] = ca;
    }
    __syncthreads();

    // ---- scan-1: per-thread warm-up (contractive, slope <= 1-ev = 0.71/step) ----
    const int i0 = row0 + t * S_OUT;
    const int rb = i0 - shift;
    int rr = rb - WARM; if (rr < 0) rr = 0;
    float c = (rr == 0) ? pp0 : 0.0f;
    const int rs = (rb < 0) ? 0 : rb;
    for (; rr < rs; ++rr)
        c = pp_step(c, s_prec[SW(rr - row0 + HALO)], mr, miss, omev, evc);

    // ---- q + local (zero carry-in) scan-2; outputs held in registers ----
    float outl[S_OUT];
    float h = 0.0f;
    for (int j = 0; j < S_OUT; ++j) {
        const int i = i0 + j;
        const int r = i - shift;
        float qs = 0.0f;
        if (r >= 0) {
            float pre = fmaxf(c, 0.0f);                 // relu'd prec_pre; carry stays raw
            int ci = r - row0 + 4;
            float qg = fmaxf(pre * s_cG[SW(ci)], 0.0f);
            float di = fmaxf(fmaf(pre, 0.001f, -dp), 0.0f);
            float qi = fmaxf(s_cA[SW(ci)] * __powf(di, 5.0f / 3.0f), 0.0f);
            qs = qg + qi;
            c = pp_step(c, s_prec[SW(r - row0 + HALO)], mr, miss, omev, evc);
        }
        h = fmaf(wr1, h, wr2 * qs);     // q_shift[0]=0 keeps h=0 through i=0 (matches ref)
        outl[j] = (ep > 10) ? fmaf(wz1, h, wz2 * qs) : qs;
    }

    // coalesced store: 2 x float4 per thread, 32B-aligned
    float4* op = reinterpret_cast<float4*>(out + i0);
    op[0] = make_float4(outl[0], outl[1], outl[2], outl[3]);
    op[1] = make_float4(outl[4], outl[5], outl[6], outl[7]);

    // thread aggregate (zero when epoch<=10 so fix-up kernel becomes a pure no-op)
    float Bv = (ep > 10) ? h : 0.0f;
    s_B[t] = Bv;
    Bthr[b * BLK + t] = Bv;
    __syncthreads();
    if (t == 0) {
        const float at = powf(wr1, (float)S_OUT);
        float acc = 0.0f;
        for (int u = 0; u < BLK; ++u) acc = fmaf(at, acc, s_B[u]);
        Bblk[b] = acc;
    }
}

// Cross-block carry propagation + correction: out[i0+j] += wz1 * wr1^(j+1) * h_in.
// Barrier-separated second launch; carries computed thread-parallel (no polling).
__global__ __launch_bounds__(BLK) void k_fix(
    float* __restrict__ out,
    const float* __restrict__ Bthr, const float* __restrict__ Bblk,
    const float* __restrict__ wr1p, const float* __restrict__ wz1p)
{
    __shared__ float sBb[NB];
    __shared__ float sB[BLK];
    __shared__ float carr[BLK];
    __shared__ float sred[BLK];
    const int b = blockIdx.x, t = threadIdx.x;
    const float wr1 = *wr1p, wz1 = *wz1p;
    for (int u = t; u < NB; u += BLK) sBb[u] = Bblk[u];
    sB[t] = Bthr[b * BLK + t];
    __syncthreads();

    // carry into block b = sum_{u<b} agg_u * ab^(b-1-u) — thread-parallel + tree reduce
    const float ab = powf(wr1, (float)R_BLOCK);     // wr1=1 -> exactly 1
    const float at = powf(wr1, (float)S_OUT);
    float partial = 0.0f;
    for (int u = t; u < b; u += BLK)
        partial = fmaf(sBb[u], powf(ab, (float)(b - 1 - u)), partial);
    sred[t] = partial;
    __syncthreads();
    for (int off = BLK / 2; off > 0; off >>= 1) {
        if (t < off) sred[t] += sred[t + off];
        __syncthreads();
    }
    // per-thread carry: serial 256-fma prefix on t0 (~0.4 us, blocks run in parallel)
    if (t == 0) {
        float cth = sred[0];
        for (int u = 0; u < BLK; ++u) { carr[u] = cth; cth = fmaf(at, cth, sB[u]); }
    }
    __syncthreads();

    float hin = carr[t];
    if (hin != 0.0f) {                  // epoch<=10 or true-zero carry: exact no-op
        float4* op = reinterpret_cast<float4*>(out + b * R_BLOCK + t * S_OUT);
        float4 v0 = op[0], v1 = op[1];
        float p = hin * wz1;
        p *= wr1; v0.x += p; p *= wr1; v0.y += p; p *= wr1; v0.z += p; p *= wr1; v0.w += p;
        p *= wr1; v1.x += p; p *= wr1; v1.y += p; p *= wr1; v1.z += p; p *= wr1; v1.w += p;
        op[0] = v0;
        op[1] = v1;
    }
}

extern "C" void kernel_launch(void* const* d_in, const int* in_sizes, int n_in,
                              void* d_out, int out_size, void* d_ws, size_t ws_size,
                              hipStream_t stream) {
    const float* x = (const float*)d_in[0];
    float* out  = (float*)d_out;
    float* Bthr = (float*)d_ws;            // NTH floats (512 KB)
    float* Bblk = Bthr + NTH;              // NB floats

    k_main<<<NB, BLK, 0, stream>>>(x,
        (const float*)d_in[1],  (const float*)d_in[2],  (const float*)d_in[3],
        (const float*)d_in[4],  (const float*)d_in[5],  (const float*)d_in[6],
        (const float*)d_in[7],  (const float*)d_in[8],  (const float*)d_in[9],
        (const float*)d_in[10], (const float*)d_in[11], (const float*)d_in[12],
        (const float*)d_in[13], (const int*)d_in[14],
        out, Bthr, Bblk);

    k_fix<<<NB, BLK, 0, stream>>>(out, Bthr, Bblk,
        (const float*)d_in[10], (const float*)d_in[12]);
}